// Round 10
// baseline (177.824 us; speedup 1.0000x reference)
//
#include <hip/hip_runtime.h>

#define AS1 __attribute__((address_space(1)))
#define AS3 __attribute__((address_space(3)))

typedef _Float16 f16x8 __attribute__((ext_vector_type(8)));
typedef float f32x4 __attribute__((ext_vector_type(4)));

static constexpr int S = 4;
static constexpr int NATOMS = 32768;
static constexpr int FIN = 512;
static constexpr int H = 256;
static constexpr int BM = 128;   // atoms per block
static constexpr int HSTR = 264; // h plane: 256 cols + 8 pad fp16 (528B rows, 2-way banks)

// ---- weight packing: fp32 [S][K][H] -> fragment-major fp16 (1-term) ----
// frag = 64 lanes x 8 fp16. Element (lane,j): k = kt*32+(lane>>4)*8+j ; n = ntile*16+(lane&15)
__global__ void pack_w(const float* __restrict__ W, _Float16* __restrict__ dst, int KT) {
    int idx = blockIdx.x * 256 + threadIdx.x;
    int j = idx & 7;
    int lane = (idx >> 3) & 63;
    int rest = idx >> 9;
    int kt = rest % KT;
    int t2 = rest / KT;            // s*16 + ntile
    int K = KT * 32;
    int k = kt * 32 + (lane >> 4) * 8 + j;
    int n = (t2 & 15) * 16 + (lane & 15);
    int s = t2 >> 4;
    dst[(((size_t)t2 * KT + kt) * 64 + lane) * 8 + j] = (_Float16)W[((size_t)s * K + k) * H + n];
}

__global__ void init_out(float* __restrict__ out, const float* __restrict__ shift, int n) {
    int i = blockIdx.x * 256 + threadIdx.x;
    if (i < n) out[i] = shift[0];
}

__global__ __launch_bounds__(512, 2) void fused_mlp(
    const float* __restrict__ X, const int* __restrict__ ids,
    const _Float16* __restrict__ W1p, const _Float16* __restrict__ W2p,
    const _Float16* __restrict__ W3p,
    const float* __restrict__ b1, const float* __restrict__ b2,
    const float* __restrict__ b3,
    const float* __restrict__ W4, const float* __restrict__ b4,
    float* __restrict__ out)
{
    // LDS map: [0,67584): h plane [128][264] fp16, ALIASED over X tri-buffer
    //          3 x [128][32] fp32 (49152B). [67584,116736): W tri-buffer
    //          3 x 16KB fp16 frag-major. [116736,118784): e_lds [4][128] f32.
    __shared__ __align__(16) unsigned char smem_raw[118784];
    float*     Xlds = (float*)smem_raw;
    _Float16*  hb   = (_Float16*)smem_raw;
    _Float16*  Wlds = (_Float16*)(smem_raw + 67584);
    float*     e_lds = (float*)(smem_raw + 116736);

    const int s = blockIdx.y;
    const int tile = blockIdx.x;
    const int tid = threadIdx.x;
    const int w = tid >> 6, lane = tid & 63;
    const int wm = w >> 2;         // 0..1: M-half (64 rows)
    const int wn = w & 3;          // 0..3: N-slice (64 cols)
    const int g = lane >> 4, mh = lane & 15;

    const float* Xb = X + (size_t)(s * NATOMS + tile * BM) * FIN;

    f32x4 acc[4][4];
#pragma unroll
    for (int i = 0; i < 4; ++i)
#pragma unroll
        for (int j = 0; j < 4; ++j)
            acc[i][j] = f32x4{0.f, 0.f, 0.f, 0.f};

    // X chunk [128 rows][32 cols fp32] = 16KB, granule(16B)-XOR-swizzled source:
    // LDS[row][q] holds global granule q^(row&7)  -> A reads 2-way bank-free.
    auto issueX = [&](int c) {
        float* xb = Xlds + (c % 3) * 4096;
#pragma unroll
        for (int i = 0; i < 2; ++i) {
            int f = i * 512 + tid;
            int row = f >> 3, q = f & 7;
            int gg = q ^ (row & 7);
            __builtin_amdgcn_global_load_lds(
                (const AS1 unsigned int*)(Xb + (size_t)row * FIN + c * 32 + gg * 4),
                (AS3 unsigned int*)(xb + f * 4), 16, 0, 0);
        }
    };
    // W chunk = one kt (32 k) x 16 ntiles, frag-major linear (16KB)
    auto issueW = [&](const _Float16* Wp, int KT, int c, int j) {
        _Float16* wb = Wlds + (j % 3) * 8192;
#pragma unroll
        for (int i = 0; i < 2; ++i) {
            int f = i * 512 + tid;
            int nt = f >> 6, ln = f & 63;
            __builtin_amdgcn_global_load_lds(
                (const AS1 unsigned int*)(Wp + ((((size_t)(s * 16 + nt)) * KT + c) * 64 + ln) * 8),
                (AS3 unsigned int*)(wb + f * 8), 16, 0, 0);
        }
    };

    auto l1comp = [&](int c) {
        const float* xb = Xlds + (c % 3) * 4096;
        const _Float16* wb = Wlds + (c % 3) * 8192;   // L1: j == c
        f16x8 a[4];
#pragma unroll
        for (int mt = 0; mt < 4; ++mt) {
            int row = wm * 64 + mt * 16 + mh;
            int s0 = (2 * g) ^ (row & 7);
            int s1 = (2 * g + 1) ^ (row & 7);
            f32x4 u = *(const f32x4*)(xb + row * 32 + s0 * 4);
            f32x4 v = *(const f32x4*)(xb + row * 32 + s1 * 4);
            f16x8 a8;
#pragma unroll
            for (int j = 0; j < 4; ++j) {
                a8[j] = (_Float16)u[j];
                a8[j + 4] = (_Float16)v[j];
            }
            a[mt] = a8;
        }
        __builtin_amdgcn_s_setprio(1);
#pragma unroll
        for (int nt = 0; nt < 4; ++nt) {
            f16x8 b = *(const f16x8*)(wb + ((wn * 4 + nt) * 64 + lane) * 8);
#pragma unroll
            for (int mt = 0; mt < 4; ++mt)
                acc[mt][nt] = __builtin_amdgcn_mfma_f32_16x16x32_f16(a[mt], b, acc[mt][nt], 0, 0, 0);
        }
        __builtin_amdgcn_s_setprio(0);
    };

    auto l23comp = [&](int c, int j) {
        const _Float16* wb = Wlds + (j % 3) * 8192;
        f16x8 a[4];
#pragma unroll
        for (int mt = 0; mt < 4; ++mt)
            a[mt] = *(const f16x8*)(hb + (wm * 64 + mt * 16 + mh) * HSTR + c * 32 + g * 8);
        __builtin_amdgcn_s_setprio(1);
#pragma unroll
        for (int nt = 0; nt < 4; ++nt) {
            f16x8 b = *(const f16x8*)(wb + ((wn * 4 + nt) * 64 + lane) * 8);
#pragma unroll
            for (int mt = 0; mt < 4; ++mt)
                acc[mt][nt] = __builtin_amdgcn_mfma_f32_16x16x32_f16(a[mt], b, acc[mt][nt], 0, 0, 0);
        }
        __builtin_amdgcn_s_setprio(0);
    };

    auto silu_epilogue = [&](const float* bias) {
        float bv[4];
#pragma unroll
        for (int nt = 0; nt < 4; ++nt) bv[nt] = bias[s * H + wn * 64 + nt * 16 + mh];
#pragma unroll
        for (int mt = 0; mt < 4; ++mt)
#pragma unroll
            for (int nt = 0; nt < 4; ++nt)
#pragma unroll
                for (int r = 0; r < 4; ++r) {
                    float v = acc[mt][nt][r] + bv[nt];
                    v = __fdividef(v, 1.f + __expf(-v));
                    hb[(wm * 64 + mt * 16 + g * 4 + r) * HSTR + wn * 64 + nt * 16 + mh] = (_Float16)v;
                    acc[mt][nt][r] = 0.f;
                }
    };

    // ---------------- L1: 16 chunks, X+W distance-2, uniform vmcnt(4) ----------------
    issueW(W1p, 16, 0, 0); issueX(0);
    issueW(W1p, 16, 1, 1); issueX(1);
#pragma unroll
    for (int c = 0; c < 16; ++c) {
        if (c < 15) asm volatile("s_waitcnt vmcnt(4)" ::: "memory");
        else        asm volatile("s_waitcnt vmcnt(2)" ::: "memory");
        __builtin_amdgcn_s_barrier();
        if (c <= 13)      { issueW(W1p, 16, c + 2, c + 2); issueX(c + 2); }
        else if (c == 14) issueW(W2p, 8, 0, 16);
        else              issueW(W2p, 8, 1, 17);
        l1comp(c);
    }
    __builtin_amdgcn_s_barrier();   // all waves done reading X bufs
    silu_epilogue(b1);              // h overwrites X region
    asm volatile("s_waitcnt lgkmcnt(0)" ::: "memory");
    __builtin_amdgcn_s_barrier();

    // ---------------- L2: 8 chunks (j = 16+c), vmcnt(2) ----------------
#pragma unroll
    for (int c = 0; c < 8; ++c) {
        asm volatile("s_waitcnt vmcnt(2)" ::: "memory");
        __builtin_amdgcn_s_barrier();
        if (c <= 5)       issueW(W2p, 8, c + 2, 18 + c);
        else if (c == 6)  issueW(W3p, 8, 0, 24);
        else              issueW(W3p, 8, 1, 25);
        l23comp(c, 16 + c);
    }
    __builtin_amdgcn_s_barrier();   // all h1 reads done
    silu_epilogue(b2);
    asm volatile("s_waitcnt lgkmcnt(0)" ::: "memory");
    __builtin_amdgcn_s_barrier();

    // ---------------- L3: 8 chunks (j = 24+c) ----------------
#pragma unroll
    for (int c = 0; c < 8; ++c) {
        if (c < 7) asm volatile("s_waitcnt vmcnt(2)" ::: "memory");
        else       asm volatile("s_waitcnt vmcnt(0)" ::: "memory");
        __builtin_amdgcn_s_barrier();
        if (c <= 5) issueW(W3p, 8, c + 2, 26 + c);
        l23comp(c, 24 + c);
    }

    // ---------------- L3 activation + L4 dot + reduce + scatter ----------------
    {
        float bv[4], w4v[4];
#pragma unroll
        for (int nt = 0; nt < 4; ++nt) {
            int col = wn * 64 + nt * 16 + mh;
            bv[nt] = b3[s * H + col];
            w4v[nt] = W4[s * H + col];
        }
#pragma unroll
        for (int mt = 0; mt < 4; ++mt)
#pragma unroll
            for (int r = 0; r < 4; ++r) {
                float v = 0.f;
#pragma unroll
                for (int nt = 0; nt < 4; ++nt) {
                    float h = acc[mt][nt][r] + bv[nt];
                    h = __fdividef(h, 1.f + __expf(-h));
                    v += h * w4v[nt];
                }
                v += __shfl_xor(v, 1);
                v += __shfl_xor(v, 2);
                v += __shfl_xor(v, 4);
                v += __shfl_xor(v, 8);
                if (mh == r) e_lds[wn * BM + wm * 64 + mt * 16 + g * 4 + r] = v;
            }
    }
    __syncthreads();
    if (tid < BM) {
        float e = b4[s] + e_lds[tid] + e_lds[BM + tid] + e_lds[2 * BM + tid] + e_lds[3 * BM + tid];
        int id = ids[s * NATOMS + tile * BM + tid];
        atomicAdd(&out[id], e);
    }
}

extern "C" void kernel_launch(void* const* d_in, const int* in_sizes, int n_in,
                              void* d_out, int out_size, void* d_ws, size_t ws_size,
                              hipStream_t stream) {
    const float* X   = (const float*)d_in[0];
    const int*   ids = (const int*)d_in[1];
    const float* W1  = (const float*)d_in[2];
    const float* b1  = (const float*)d_in[3];
    const float* W2  = (const float*)d_in[4];
    const float* b2  = (const float*)d_in[5];
    const float* W3  = (const float*)d_in[6];
    const float* b3  = (const float*)d_in[7];
    const float* W4  = (const float*)d_in[8];
    const float* b4  = (const float*)d_in[9];
    const float* shift = (const float*)d_in[10];

    // packed fp16 weights (1-term): W1p 1MB, W2p 512KB, W3p 512KB
    _Float16* W1p = (_Float16*)d_ws;
    _Float16* W2p = W1p + (size_t)S * 16 * 16 * 512;
    _Float16* W3p = W2p + (size_t)S * 16 * 8 * 512;

    pack_w<<<2048, 256, 0, stream>>>(W1, W1p, 16);
    pack_w<<<1024, 256, 0, stream>>>(W2, W2p, 8);
    pack_w<<<1024, 256, 0, stream>>>(W3, W3p, 8);

    init_out<<<(out_size + 255) / 256, 256, 0, stream>>>((float*)d_out, shift, out_size);

    dim3 grid(NATOMS / BM, S);
    fused_mlp<<<grid, 512, 0, stream>>>(X, ids, W1p, W2p, W3p, b1, b2, b3, W4, b4,
                                        (float*)d_out);
}

// Round 11
// 162.181 us; speedup vs baseline: 1.0965x; 1.0965x over previous
//
#include <hip/hip_runtime.h>

typedef _Float16 f16x8 __attribute__((ext_vector_type(8)));
typedef _Float16 f16x4 __attribute__((ext_vector_type(4)));
typedef float f32x4 __attribute__((ext_vector_type(4)));

static constexpr int S = 4;
static constexpr int NATOMS = 32768;
static constexpr int FIN = 512;
static constexpr int H = 256;
static constexpr int BM = 64;    // atoms per block
static constexpr int XSTR = 72;  // fp16/row (144B): 2-way banks, free
static constexpr int HSTR = 264; // h plane: 256 cols + 8 pad fp16 (528B rows, 2-way)

// ---- weight packing: fp32 [S][K][H] -> per-wave contiguous consumption-order fp16 stream
// Stream layout: [s][wn=ntile>>1][p][lane][8], frag = 64 lanes x 8 fp16.
// L1 (l1=1, KT=16): p = (kt>>1)*4 + (kt&1)*2 + (ntile&1)   (kernel order: c, ks, nt)
// L2/L3 (KT=8):     p = kt*2 + (ntile&1)
__global__ void pack_w(const float* __restrict__ W, _Float16* __restrict__ dst, int KT, int l1) {
    int idx = blockIdx.x * 256 + threadIdx.x;
    int j = idx & 7;
    int lane = (idx >> 3) & 63;
    int rest = idx >> 9;
    int kt = rest % KT;
    int t2 = rest / KT;            // s*16 + ntile
    int K = KT * 32;
    int k = kt * 32 + (lane >> 4) * 8 + j;
    int ntile = t2 & 15;
    int s = t2 >> 4;
    int n = ntile * 16 + (lane & 15);
    int p = l1 ? ((kt >> 1) * 4 + (kt & 1) * 2 + (ntile & 1))
               : (kt * 2 + (ntile & 1));
    size_t o = ((((size_t)(s * 8 + (ntile >> 1))) * (KT * 2) + p) * 64 + lane) * 8 + j;
    dst[o] = (_Float16)W[((size_t)s * K + k) * H + n];
}

__global__ void init_out(float* __restrict__ out, const float* __restrict__ shift, int n) {
    int i = blockIdx.x * 256 + threadIdx.x;
    if (i < n) out[i] = shift[0];
}

__global__ __launch_bounds__(512, 4) void fused_mlp(
    const float* __restrict__ X, const int* __restrict__ ids,
    const _Float16* __restrict__ W1p, const _Float16* __restrict__ W2p,
    const _Float16* __restrict__ W3p,
    const float* __restrict__ b1, const float* __restrict__ b2,
    const float* __restrict__ b3,
    const float* __restrict__ W4, const float* __restrict__ b4,
    float* __restrict__ out)
{
    // union: X fp16 TRIPLE buffer [3][64][72] (27648B) aliased by h fp16 plane
    // [64][264] (33792B). h written only after all layer-1 LDS reads are done.
    __shared__ _Float16 smem[BM * HSTR];
    __shared__ float e_lds[8][BM];

    const int s = blockIdx.y;
    const int tile = blockIdx.x;
    const int tid = threadIdx.x;
    const int rw = __builtin_amdgcn_readfirstlane(tid >> 6);  // wave idx -> SGPR
    const int lane = tid & 63;
    const int g = lane >> 4;
    const int mh = lane & 15;
    const int srow = tid >> 3;     // staging row (64 rows, 8 threads/row)
    const int cq = tid & 7;        // staging col group (8 floats each)

    const float* Xb = X + (size_t)(s * NATOMS + tile * BM) * FIN;
    _Float16* hb = smem;

    // per-wave contiguous weight streams (SGPR base + lane*16B + constexpr imm)
    const _Float16* Wb1 = W1p + ((size_t)(s * 8 + rw)) * (32 * 512) + lane * 8;
    const _Float16* Wb2 = W2p + ((size_t)(s * 8 + rw)) * (16 * 512) + lane * 8;
    const _Float16* Wb3 = W3p + ((size_t)(s * 8 + rw)) * (16 * 512) + lane * 8;

    f32x4 acc[4][2];
#pragma unroll
    for (int i = 0; i < 4; ++i)
#pragma unroll
        for (int j = 0; j < 2; ++j)
            acc[i][j] = f32x4{0.f, 0.f, 0.f, 0.f};

    // ---- layer-1 staging: global->reg (f32) -> cvt once -> LDS (f16) ----
    f32x4 ld[4][2];
    auto loadc = [&](int slot, int c) {
        const float* p = Xb + (size_t)srow * FIN + c * 64 + cq * 8;
        ld[slot][0] = *(const f32x4*)(p);
        ld[slot][1] = *(const f32x4*)(p + 4);
    };
    auto storec = [&](int slot, int c) {
        _Float16* xb = smem + (c % 3) * (BM * XSTR);   // c constexpr under unroll
#pragma unroll
        for (int i = 0; i < 2; ++i) {
            f16x4 v;
#pragma unroll
            for (int j = 0; j < 4; ++j) v[j] = (_Float16)ld[slot][i][j];
            *(f16x4*)(xb + srow * XSTR + cq * 8 + i * 4) = v;
        }
    };
    auto l1mfma = [&](int c) {
        const _Float16* xb = smem + (c % 3) * (BM * XSTR);
#pragma unroll
        for (int ks = 0; ks < 2; ++ks) {
            f16x8 a[4];
#pragma unroll
            for (int mt = 0; mt < 4; ++mt)
                a[mt] = *(const f16x8*)(xb + (mt * 16 + mh) * XSTR + (ks * 4 + g) * 8);
            __builtin_amdgcn_s_setprio(1);
#pragma unroll
            for (int nt = 0; nt < 2; ++nt) {
                f16x8 b = *(const f16x8*)(Wb1 + (c * 4 + ks * 2 + nt) * 512);
#pragma unroll
                for (int mt = 0; mt < 4; ++mt)
                    acc[mt][nt] = __builtin_amdgcn_mfma_f32_16x16x32_f16(a[mt], b, acc[mt][nt], 0, 0, 0);
            }
            __builtin_amdgcn_s_setprio(0);
        }
    };

    // ---------------- layer 1: [64x512] @ [512x256], prefetch distance 3 ----------------
    loadc(0, 0);
    loadc(1, 1);
    loadc(2, 2);
    loadc(3, 3);
    storec(0, 0);
    asm volatile("s_waitcnt lgkmcnt(0)" ::: "memory");
    __builtin_amdgcn_s_barrier();
#pragma unroll
    for (int c = 0; c < 8; ++c) {
        if (c < 7) storec((c + 1) & 3, c + 1);  // slot (c+1)&3 holds chunk c+1
        if (c < 4) loadc(c & 3, c + 4);         // slot's old chunk already in LDS
        l1mfma(c);
        asm volatile("s_waitcnt lgkmcnt(0)" ::: "memory");
        __builtin_amdgcn_s_barrier();
    }
    __syncthreads();  // full drain before h overwrites the X union

    // bias + silu -> h1 (fp16 plane)
    {
        float bv[2];
#pragma unroll
        for (int nt = 0; nt < 2; ++nt) bv[nt] = b1[s * H + rw * 32 + nt * 16 + mh];
#pragma unroll
        for (int mt = 0; mt < 4; ++mt)
#pragma unroll
            for (int nt = 0; nt < 2; ++nt)
#pragma unroll
                for (int r = 0; r < 4; ++r) {
                    float v = acc[mt][nt][r] + bv[nt];
                    v = __fdividef(v, 1.f + __expf(-v));
                    hb[(mt * 16 + g * 4 + r) * HSTR + rw * 32 + nt * 16 + mh] = (_Float16)v;
                    acc[mt][nt][r] = 0.f;
                }
    }
    __syncthreads();

    // ---------------- layers 2 and 3: [64x256] @ [256x256] ----------------
    for (int l = 0; l < 2; ++l) {
        const _Float16* Wb = l ? Wb3 : Wb2;
#pragma unroll
        for (int ks = 0; ks < 8; ++ks) {
            f16x8 a[4];
#pragma unroll
            for (int mt = 0; mt < 4; ++mt)
                a[mt] = *(const f16x8*)(hb + (mt * 16 + mh) * HSTR + ks * 32 + g * 8);
            __builtin_amdgcn_s_setprio(1);
#pragma unroll
            for (int nt = 0; nt < 2; ++nt) {
                f16x8 b = *(const f16x8*)(Wb + (ks * 2 + nt) * 512);
#pragma unroll
                for (int mt = 0; mt < 4; ++mt)
                    acc[mt][nt] = __builtin_amdgcn_mfma_f32_16x16x32_f16(a[mt], b, acc[mt][nt], 0, 0, 0);
            }
            __builtin_amdgcn_s_setprio(0);
        }
        __syncthreads();  // all reads of h done before overwrite
        if (l == 0) {
            float bv[2];
#pragma unroll
            for (int nt = 0; nt < 2; ++nt) bv[nt] = b2[s * H + rw * 32 + nt * 16 + mh];
#pragma unroll
            for (int mt = 0; mt < 4; ++mt)
#pragma unroll
                for (int nt = 0; nt < 2; ++nt)
#pragma unroll
                    for (int r = 0; r < 4; ++r) {
                        float v = acc[mt][nt][r] + bv[nt];
                        v = __fdividef(v, 1.f + __expf(-v));
                        hb[(mt * 16 + g * 4 + r) * HSTR + rw * 32 + nt * 16 + mh] = (_Float16)v;
                        acc[mt][nt][r] = 0.f;
                    }
            __syncthreads();
        }
    }

    // ---------------- layer 3 activation + layer 4 dot + reduce ----------------
    {
        float bv[2], w4v[2];
#pragma unroll
        for (int nt = 0; nt < 2; ++nt) {
            int col = rw * 32 + nt * 16 + mh;
            bv[nt] = b3[s * H + col];
            w4v[nt] = W4[s * H + col];
        }
#pragma unroll
        for (int mt = 0; mt < 4; ++mt)
#pragma unroll
            for (int r = 0; r < 4; ++r) {
                float v = 0.f;
#pragma unroll
                for (int nt = 0; nt < 2; ++nt) {
                    float h = acc[mt][nt][r] + bv[nt];
                    h = __fdividef(h, 1.f + __expf(-h));
                    v += h * w4v[nt];
                }
                v += __shfl_xor(v, 1);
                v += __shfl_xor(v, 2);
                v += __shfl_xor(v, 4);
                v += __shfl_xor(v, 8);
                if (mh == r) e_lds[rw][mt * 16 + g * 4 + r] = v;
            }
    }
    __syncthreads();
    if (tid < BM) {
        float e = b4[s];
#pragma unroll
        for (int j = 0; j < 8; ++j) e += e_lds[j][tid];
        int id = ids[s * NATOMS + tile * BM + tid];
        atomicAdd(&out[id], e);
    }
}

extern "C" void kernel_launch(void* const* d_in, const int* in_sizes, int n_in,
                              void* d_out, int out_size, void* d_ws, size_t ws_size,
                              hipStream_t stream) {
    const float* X   = (const float*)d_in[0];
    const int*   ids = (const int*)d_in[1];
    const float* W1  = (const float*)d_in[2];
    const float* b1  = (const float*)d_in[3];
    const float* W2  = (const float*)d_in[4];
    const float* b2  = (const float*)d_in[5];
    const float* W3  = (const float*)d_in[6];
    const float* b3  = (const float*)d_in[7];
    const float* W4  = (const float*)d_in[8];
    const float* b4  = (const float*)d_in[9];
    const float* shift = (const float*)d_in[10];

    // packed fp16 weights (per-wave streams): W1p 1MB, W2p 512KB, W3p 512KB
    _Float16* W1p = (_Float16*)d_ws;
    _Float16* W2p = W1p + (size_t)S * 8 * 32 * 512;
    _Float16* W3p = W2p + (size_t)S * 8 * 16 * 512;

    pack_w<<<2048, 256, 0, stream>>>(W1, W1p, 16, 1);
    pack_w<<<1024, 256, 0, stream>>>(W2, W2p, 8, 0);
    pack_w<<<1024, 256, 0, stream>>>(W3, W3p, 8, 0);

    init_out<<<(out_size + 255) / 256, 256, 0, stream>>>((float*)d_out, shift, out_size);

    dim3 grid(NATOMS / BM, S);
    fused_mlp<<<grid, 512, 0, stream>>>(X, ids, W1p, W2p, W3p, b1, b2, b3, W4, b4,
                                        (float*)d_out);
}

// Round 12
// 149.693 us; speedup vs baseline: 1.1879x; 1.0834x over previous
//
#include <hip/hip_runtime.h>

typedef _Float16 f16x8 __attribute__((ext_vector_type(8)));
typedef _Float16 f16x4 __attribute__((ext_vector_type(4)));
typedef float f32x4 __attribute__((ext_vector_type(4)));

static constexpr int S = 4;
static constexpr int NATOMS = 32768;
static constexpr int FIN = 512;
static constexpr int H = 256;
static constexpr int BM = 64;    // atoms per block
static constexpr int XSTR = 72;  // fp16/row (144B): 2-way banks, free
static constexpr int HSTR = 264; // h plane: 256 cols + 8 pad fp16 (528B rows, 2-way)
static constexpr int NSTRUCT = 512;
static constexpr int RBLK = 128; // reduce1 blocks
static constexpr int APB = (S * NATOMS) / RBLK;  // atoms per reduce1 block = 1024

// ---- weight packing: fp32 [S][K][H] -> per-wave contiguous consumption-order fp16 stream
// Stream layout: [s][wn=ntile>>1][p][lane][8], frag = 64 lanes x 8 fp16.
// L1 (l1=1, KT=16): p = (kt>>1)*4 + (kt&1)*2 + (ntile&1)   (kernel order: c, ks, nt)
// L2/L3 (KT=8):     p = kt*2 + (ntile&1)
__global__ void pack_w(const float* __restrict__ W, _Float16* __restrict__ dst, int KT, int l1) {
    int idx = blockIdx.x * 256 + threadIdx.x;
    int j = idx & 7;
    int lane = (idx >> 3) & 63;
    int rest = idx >> 9;
    int kt = rest % KT;
    int t2 = rest / KT;            // s*16 + ntile
    int K = KT * 32;
    int k = kt * 32 + (lane >> 4) * 8 + j;
    int ntile = t2 & 15;
    int s = t2 >> 4;
    int n = ntile * 16 + (lane & 15);
    int p = l1 ? ((kt >> 1) * 4 + (kt & 1) * 2 + (ntile & 1))
               : (kt * 2 + (ntile & 1));
    size_t o = ((((size_t)(s * 8 + (ntile >> 1))) * (KT * 2) + p) * 64 + lane) * 8 + j;
    dst[o] = (_Float16)W[((size_t)s * K + k) * H + n];
}

__global__ __launch_bounds__(512, 4) void fused_mlp(
    const float* __restrict__ X,
    const _Float16* __restrict__ W1p, const _Float16* __restrict__ W2p,
    const _Float16* __restrict__ W3p,
    const float* __restrict__ b1, const float* __restrict__ b2,
    const float* __restrict__ b3,
    const float* __restrict__ W4, const float* __restrict__ b4,
    float* __restrict__ Eout)
{
    // union: X fp16 QUAD... triple buffer [3][64][72] aliased by h fp16 plane
    // [64][264] (33792B). h written only after all layer-1 LDS reads are done.
    __shared__ _Float16 smem[BM * HSTR];
    __shared__ float e_lds[8][BM];

    const int s = blockIdx.y;
    const int tile = blockIdx.x;
    const int tid = threadIdx.x;
    const int rw = __builtin_amdgcn_readfirstlane(tid >> 6);  // wave idx -> SGPR
    const int lane = tid & 63;
    const int g = lane >> 4;
    const int mh = lane & 15;
    const int srow = tid >> 3;     // staging row (64 rows, 8 threads/row)
    const int cq = tid & 7;        // staging col group (8 floats each)

    const float* Xb = X + (size_t)(s * NATOMS + tile * BM) * FIN;
    _Float16* hb = smem;

    // per-wave contiguous weight streams (SGPR base + lane*16B + constexpr imm)
    const _Float16* Wb1 = W1p + ((size_t)(s * 8 + rw)) * (32 * 512) + lane * 8;
    const _Float16* Wb2 = W2p + ((size_t)(s * 8 + rw)) * (16 * 512) + lane * 8;
    const _Float16* Wb3 = W3p + ((size_t)(s * 8 + rw)) * (16 * 512) + lane * 8;

    f32x4 acc[4][2];
#pragma unroll
    for (int i = 0; i < 4; ++i)
#pragma unroll
        for (int j = 0; j < 2; ++j)
            acc[i][j] = f32x4{0.f, 0.f, 0.f, 0.f};

    // ---- layer-1 staging: global->reg (f32) -> cvt once -> LDS (f16) ----
    f32x4 ld[4][2];
    auto loadc = [&](int slot, int c) {
        const float* p = Xb + (size_t)srow * FIN + c * 64 + cq * 8;
        ld[slot][0] = *(const f32x4*)(p);
        ld[slot][1] = *(const f32x4*)(p + 4);
    };
    auto storec = [&](int slot, int c) {
        _Float16* xb = smem + (c % 3) * (BM * XSTR);   // c constexpr under unroll
#pragma unroll
        for (int i = 0; i < 2; ++i) {
            f16x4 v;
#pragma unroll
            for (int j = 0; j < 4; ++j) v[j] = (_Float16)ld[slot][i][j];
            *(f16x4*)(xb + srow * XSTR + cq * 8 + i * 4) = v;
        }
    };
    auto l1mfma = [&](int c) {
        const _Float16* xb = smem + (c % 3) * (BM * XSTR);
#pragma unroll
        for (int ks = 0; ks < 2; ++ks) {
            f16x8 a[4];
#pragma unroll
            for (int mt = 0; mt < 4; ++mt)
                a[mt] = *(const f16x8*)(xb + (mt * 16 + mh) * XSTR + (ks * 4 + g) * 8);
            __builtin_amdgcn_s_setprio(1);
#pragma unroll
            for (int nt = 0; nt < 2; ++nt) {
                f16x8 b = *(const f16x8*)(Wb1 + (c * 4 + ks * 2 + nt) * 512);
#pragma unroll
                for (int mt = 0; mt < 4; ++mt)
                    acc[mt][nt] = __builtin_amdgcn_mfma_f32_16x16x32_f16(a[mt], b, acc[mt][nt], 0, 0, 0);
            }
            __builtin_amdgcn_s_setprio(0);
        }
    };

    // ---------------- layer 1: [64x512] @ [512x256], prefetch distance 3 ----------------
    loadc(0, 0);
    loadc(1, 1);
    loadc(2, 2);
    loadc(3, 3);
    storec(0, 0);
    asm volatile("s_waitcnt lgkmcnt(0)" ::: "memory");
    __builtin_amdgcn_s_barrier();
#pragma unroll
    for (int c = 0; c < 8; ++c) {
        if (c < 7) storec((c + 1) & 3, c + 1);  // slot (c+1)&3 holds chunk c+1
        if (c < 4) loadc(c & 3, c + 4);         // slot's old chunk already in LDS
        l1mfma(c);
        asm volatile("s_waitcnt lgkmcnt(0)" ::: "memory");
        __builtin_amdgcn_s_barrier();
    }
    __syncthreads();  // full drain before h overwrites the X union

    // bias + silu -> h1 (fp16 plane)
    {
        float bv[2];
#pragma unroll
        for (int nt = 0; nt < 2; ++nt) bv[nt] = b1[s * H + rw * 32 + nt * 16 + mh];
#pragma unroll
        for (int mt = 0; mt < 4; ++mt)
#pragma unroll
            for (int nt = 0; nt < 2; ++nt)
#pragma unroll
                for (int r = 0; r < 4; ++r) {
                    float v = acc[mt][nt][r] + bv[nt];
                    v = __fdividef(v, 1.f + __expf(-v));
                    hb[(mt * 16 + g * 4 + r) * HSTR + rw * 32 + nt * 16 + mh] = (_Float16)v;
                    acc[mt][nt][r] = 0.f;
                }
    }
    __syncthreads();

    // ---------------- layers 2 and 3: [64x256] @ [256x256] ----------------
    for (int l = 0; l < 2; ++l) {
        const _Float16* Wb = l ? Wb3 : Wb2;
#pragma unroll
        for (int ks = 0; ks < 8; ++ks) {
            f16x8 a[4];
#pragma unroll
            for (int mt = 0; mt < 4; ++mt)
                a[mt] = *(const f16x8*)(hb + (mt * 16 + mh) * HSTR + ks * 32 + g * 8);
            __builtin_amdgcn_s_setprio(1);
#pragma unroll
            for (int nt = 0; nt < 2; ++nt) {
                f16x8 b = *(const f16x8*)(Wb + (ks * 2 + nt) * 512);
#pragma unroll
                for (int mt = 0; mt < 4; ++mt)
                    acc[mt][nt] = __builtin_amdgcn_mfma_f32_16x16x32_f16(a[mt], b, acc[mt][nt], 0, 0, 0);
            }
            __builtin_amdgcn_s_setprio(0);
        }
        __syncthreads();  // all reads of h done before overwrite
        if (l == 0) {
            float bv[2];
#pragma unroll
            for (int nt = 0; nt < 2; ++nt) bv[nt] = b2[s * H + rw * 32 + nt * 16 + mh];
#pragma unroll
            for (int mt = 0; mt < 4; ++mt)
#pragma unroll
                for (int nt = 0; nt < 2; ++nt)
#pragma unroll
                    for (int r = 0; r < 4; ++r) {
                        float v = acc[mt][nt][r] + bv[nt];
                        v = __fdividef(v, 1.f + __expf(-v));
                        hb[(mt * 16 + g * 4 + r) * HSTR + rw * 32 + nt * 16 + mh] = (_Float16)v;
                        acc[mt][nt][r] = 0.f;
                    }
            __syncthreads();
        }
    }

    // ---------------- layer 3 activation + layer 4 dot + reduce ----------------
    {
        float bv[2], w4v[2];
#pragma unroll
        for (int nt = 0; nt < 2; ++nt) {
            int col = rw * 32 + nt * 16 + mh;
            bv[nt] = b3[s * H + col];
            w4v[nt] = W4[s * H + col];
        }
#pragma unroll
        for (int mt = 0; mt < 4; ++mt)
#pragma unroll
            for (int r = 0; r < 4; ++r) {
                float v = 0.f;
#pragma unroll
                for (int nt = 0; nt < 2; ++nt) {
                    float h = acc[mt][nt][r] + bv[nt];
                    h = __fdividef(h, 1.f + __expf(-h));
                    v += h * w4v[nt];
                }
                v += __shfl_xor(v, 1);
                v += __shfl_xor(v, 2);
                v += __shfl_xor(v, 4);
                v += __shfl_xor(v, 8);
                if (mh == r) e_lds[rw][mt * 16 + g * 4 + r] = v;
            }
    }
    __syncthreads();
    // plain coalesced store of per-atom energies -- NO global atomics
    if (tid < BM) {
        float e = b4[s];
#pragma unroll
        for (int j = 0; j < 8; ++j) e += e_lds[j][tid];
        Eout[(size_t)s * NATOMS + tile * BM + tid] = e;
    }
}

// stage 1: per-block private LDS histogram of 1024 atoms -> partial[512] per block
__global__ __launch_bounds__(256) void reduce1(
    const float* __restrict__ E, const int* __restrict__ ids,
    float* __restrict__ partials)
{
    __shared__ float tbl[NSTRUCT];
    const int b = blockIdx.x;
    const int tid = threadIdx.x;
    tbl[tid] = 0.f;
    tbl[tid + 256] = 0.f;
    __syncthreads();
    const int base = b * APB;
#pragma unroll
    for (int i = 0; i < APB / 256; ++i) {
        int a = base + i * 256 + tid;
        atomicAdd(&tbl[ids[a]], E[a]);   // LDS atomic: bank-local, fast
    }
    __syncthreads();
    partials[(size_t)b * NSTRUCT + tid] = tbl[tid];
    partials[(size_t)b * NSTRUCT + tid + 256] = tbl[tid + 256];
}

// stage 2: sum 128 partial tables + shift -> out
__global__ __launch_bounds__(512) void reduce2(
    const float* __restrict__ partials, const float* __restrict__ shift,
    float* __restrict__ out)
{
    const int i = threadIdx.x;
    float v = shift[0];
#pragma unroll 8
    for (int b = 0; b < RBLK; ++b) v += partials[(size_t)b * NSTRUCT + i];
    out[i] = v;
}

extern "C" void kernel_launch(void* const* d_in, const int* in_sizes, int n_in,
                              void* d_out, int out_size, void* d_ws, size_t ws_size,
                              hipStream_t stream) {
    const float* X   = (const float*)d_in[0];
    const int*   ids = (const int*)d_in[1];
    const float* W1  = (const float*)d_in[2];
    const float* b1  = (const float*)d_in[3];
    const float* W2  = (const float*)d_in[4];
    const float* b2  = (const float*)d_in[5];
    const float* W3  = (const float*)d_in[6];
    const float* b3  = (const float*)d_in[7];
    const float* W4  = (const float*)d_in[8];
    const float* b4  = (const float*)d_in[9];
    const float* shift = (const float*)d_in[10];

    // ws layout: W1p 1MB | W2p 512KB | W3p 512KB | E 512KB | partials 256KB
    _Float16* W1p = (_Float16*)d_ws;
    _Float16* W2p = W1p + (size_t)S * 8 * 32 * 512;
    _Float16* W3p = W2p + (size_t)S * 8 * 16 * 512;
    float* E = (float*)(W3p + (size_t)S * 8 * 16 * 512);
    float* partials = E + (size_t)S * NATOMS;

    pack_w<<<2048, 256, 0, stream>>>(W1, W1p, 16, 1);
    pack_w<<<1024, 256, 0, stream>>>(W2, W2p, 8, 0);
    pack_w<<<1024, 256, 0, stream>>>(W3, W3p, 8, 0);

    dim3 grid(NATOMS / BM, S);
    fused_mlp<<<grid, 512, 0, stream>>>(X, W1p, W2p, W3p, b1, b2, b3, W4, b4, E);

    reduce1<<<RBLK, 256, 0, stream>>>(E, ids, partials);
    reduce2<<<1, 512, 0, stream>>>(partials, shift, (float*)d_out);
}